// Round 4
// baseline (580.364 us; speedup 1.0000x reference)
//
#include <hip/hip_runtime.h>
#include <hip/hip_bf16.h>
#include <cstddef>
#include <cstdint>

// Problem constants (fixed by the reference)
#define BATCH 2
#define SEQ   2048
#define DIM   2048
#define HEADS 16
#define DHEAD 128
#define INNER (HEADS * DHEAD)   // 2048
#define MROWS (BATCH * SEQ)     // 4096
#define ATT_SCALE 0.08838834764831845f  // 128^-0.5
#define NEG_LOG2_10000_DIV64 (-13.287712379549449f / 64.0f)

typedef __attribute__((ext_vector_type(8))) short short8;  // 8 bf16 = 4 VGPRs
typedef __attribute__((ext_vector_type(4))) short short4v;
typedef __attribute__((ext_vector_type(4))) float f32x4;   // MFMA C/D

// fp32 -> bf16 round-to-nearest-even (bit-level)
static __device__ __forceinline__ short f2bf(float x) {
    uint32_t u = __float_as_uint(x);
    uint32_t r = (u + 0x7fffu + ((u >> 16) & 1u)) >> 16;
    return (short)r;
}
static __device__ __forceinline__ float bf2f(short s) {
    return __uint_as_float(((uint32_t)(uint16_t)s) << 16);
}

// async global->LDS, 16 B per lane; LDS dst = uniform base + lane*16
static __device__ __forceinline__ void glds16(const short* g, short* l) {
    __builtin_amdgcn_global_load_lds(
        (const __attribute__((address_space(1))) unsigned int*)g,
        (__attribute__((address_space(3))) unsigned int*)l, 16, 0, 0);
}

// chunk swizzle for unpadded LDS tiles (chunk = 16 B): phys = logical ^ SWZ(row)
static __device__ __forceinline__ int swz_row(int r) {
    return (r & 3) | ((r >> 1) & 4);   // bits {0,1,3} of row -> 8 values
}

// ---------------------------------------------------------------------------
// x fp32 -> bf16
// ---------------------------------------------------------------------------
__global__ __launch_bounds__(256) void cast_x(const float* __restrict__ x,
                                              short* __restrict__ xb) {
    int i = blockIdx.x * 256 + threadIdx.x;
    float4 v = ((const float4*)x)[i];
    short4v s = {f2bf(v.x), f2bf(v.y), f2bf(v.z), f2bf(v.w)};
    ((short4v*)xb)[i] = s;
}

// ---------------------------------------------------------------------------
// W fp32 [R][C] -> Wt bf16 [C][R]
// ---------------------------------------------------------------------------
__global__ __launch_bounds__(256) void tcast(const float* __restrict__ W,
                                             short* __restrict__ Wt,
                                             int R, int C) {
    __shared__ float tile[64][65];
    const int c0 = blockIdx.x * 64, r0 = blockIdx.y * 64;
    const int tid = threadIdx.x;
#pragma unroll
    for (int t = 0; t < 16; ++t) {
        int idx = tid + t * 256;
        int row = idx >> 6, col = idx & 63;
        tile[row][col] = W[(size_t)(r0 + row) * C + c0 + col];
    }
    __syncthreads();
#pragma unroll
    for (int t = 0; t < 16; ++t) {
        int idx = tid + t * 256;
        int r = idx >> 6, c = idx & 63;
        Wt[(size_t)(c0 + r) * R + r0 + c] = f2bf(tile[c][r]);
    }
}

// ---------------------------------------------------------------------------
// bf16 MFMA GEMM (m97 structure): C[M,N] = A[M,K] @ Bt[N,K]^T  (unchanged)
// ---------------------------------------------------------------------------
__global__ __launch_bounds__(256) void gemm_bt(const short* __restrict__ A,
                                               const short* __restrict__ Bt,
                                               void* __restrict__ Cp,
                                               int M, int N, int K, int c_bf16) {
    __shared__ __align__(16) short sA[128 * 32];
    __shared__ __align__(16) short sB[128 * 32];

    const int tid = threadIdx.x;
    const int w = tid >> 6, lane = tid & 63;
    const int ln = lane & 15, qr = lane >> 4;
    const int bm = blockIdx.y * 128, bn = blockIdx.x * 128;
    const int wm = (w >> 1) * 64, wn = (w & 1) * 64;

    const f32x4 zero4 = {0.f, 0.f, 0.f, 0.f};
    f32x4 acc[4][4];
#pragma unroll
    for (int mt = 0; mt < 4; ++mt)
#pragma unroll
        for (int nt = 0; nt < 4; ++nt) acc[mt][nt] = zero4;

    const int srow = lane >> 2;
    const int schunk = (lane & 3) * 8;
    const short* pA = A + (size_t)(bm + w * 32 + srow) * K + schunk;
    const short* pB = Bt + (size_t)(bn + w * 32 + srow) * K + schunk;
    short* lA = &sA[(w * 32) * 32];
    short* lB = &sB[(w * 32) * 32];

    for (int k0 = 0; k0 < K; k0 += 32) {
        __syncthreads();
        glds16(pA + k0, lA);
        glds16(pA + k0 + (size_t)16 * K, lA + 512);
        glds16(pB + k0, lB);
        glds16(pB + k0 + (size_t)16 * K, lB + 512);
        __syncthreads();

        short8 af[4], bfr[4];
#pragma unroll
        for (int mt = 0; mt < 4; ++mt)
            af[mt] = *(const short8*)&sA[(wm + mt * 16 + ln) * 32 + qr * 8];
#pragma unroll
        for (int nt = 0; nt < 4; ++nt)
            bfr[nt] = *(const short8*)&sB[(wn + nt * 16 + ln) * 32 + qr * 8];
#pragma unroll
        for (int mt = 0; mt < 4; ++mt)
#pragma unroll
            for (int nt = 0; nt < 4; ++nt)
                acc[mt][nt] = __builtin_amdgcn_mfma_f32_16x16x32_bf16(
                    af[mt], bfr[nt], acc[mt][nt], 0, 0, 0);
    }

    if (c_bf16) {
        short* C = (short*)Cp;
#pragma unroll
        for (int mt = 0; mt < 4; ++mt)
#pragma unroll
            for (int nt = 0; nt < 4; ++nt)
#pragma unroll
                for (int r = 0; r < 4; ++r)
                    C[(size_t)(bm + wm + mt * 16 + qr * 4 + r) * N +
                      bn + wn + nt * 16 + ln] = f2bf(acc[mt][nt][r]);
    } else {
        float* C = (float*)Cp;
#pragma unroll
        for (int mt = 0; mt < 4; ++mt)
#pragma unroll
            for (int nt = 0; nt < 4; ++nt)
#pragma unroll
                for (int r = 0; r < 4; ++r)
                    C[(size_t)(bm + wm + mt * 16 + qr * 4 + r) * N +
                      bn + wn + nt * 16 + ln] = acc[mt][nt][r];
    }
}

// ---------------------------------------------------------------------------
// RoPE kernels (unchanged from round 3)
// ---------------------------------------------------------------------------
__global__ __launch_bounds__(256) void rope_q_ip(short* __restrict__ qb) {
    int idx = blockIdx.x * 256 + threadIdx.x;
    int j = idx & 63;
    int rh = idx >> 6;
    int pos = (rh >> 4) & (SEQ - 1);
    short* row = qb + ((size_t)rh << 7);
    float a = bf2f(row[j]);
    float b = bf2f(row[j + 64]);
    float ang = (float)pos * exp2f((float)j * NEG_LOG2_10000_DIV64);
    float c = cosf(ang), s = sinf(ang);
    row[j]      = f2bf((a * c - b * s) * ATT_SCALE);
    row[j + 64] = f2bf((b * c + a * s) * ATT_SCALE);
}

__global__ __launch_bounds__(256) void rope_k_bf(const short* __restrict__ kvbb,
                                                 short* __restrict__ kb) {
    int idx = blockIdx.x * 256 + threadIdx.x;
    int j = idx & 63;
    int bn = idx >> 6;
    int pos = bn & (SEQ - 1);
    const short* row = kvbb + (size_t)bn * 256;
    short* orow = kb + ((size_t)bn << 7);
    float a = bf2f(row[j]);
    float b = bf2f(row[j + 64]);
    float ang = (float)pos * exp2f((float)j * NEG_LOG2_10000_DIV64);
    float c = cosf(ang), s = sinf(ang);
    orow[j]      = f2bf(a * c - b * s);
    orow[j + 64] = f2bf(b * c + a * s);
}

__global__ __launch_bounds__(256) void vtrans_bf(const short* __restrict__ kvbb,
                                                 short* __restrict__ vt) {
    __shared__ float tile[64][65];
    const int bb = blockIdx.x;
    const int b = bb >> 6;
    const int tile_id = bb & 63;
    const int p0 = (tile_id >> 1) * 64;
    const int d0 = (tile_id & 1) * 64;
    const int tid = threadIdx.x;
#pragma unroll
    for (int t = 0; t < 16; ++t) {
        int idx = tid + t * 256;
        int row = idx >> 6, col = idx & 63;
        tile[row][col] = bf2f(kvbb[((size_t)(b * SEQ) + p0 + row) * 256 + 128 + d0 + col]);
    }
    __syncthreads();
#pragma unroll
    for (int t = 0; t < 16; ++t) {
        int idx = tid + t * 256;
        int r = idx >> 6, c = idx & 63;
        vt[((size_t)(b * DHEAD) + d0 + r) * SEQ + p0 + c] = f2bf(tile[c][r]);
    }
}

// ---------------------------------------------------------------------------
// MFMA flash attention v2 (causal, MQA).
// Block = 256 thr = 4 waves, handles i-tile PAIR {itH=31-p, itL=p}: exactly
// 33 tile-units of compute per block -> balanced grid of 512 blocks.
// Transposed compute: S^T = K·Q^T (A=K from LDS, B=Q regs), O^T = V^T·P^T.
// A-rows of the QK MFMA use a j-interleaved map so the S^T C-layout is
// directly the PV B-fragment layout: P stays in registers (no LDS roundtrip).
// K/V staged once per j-tile via global_load_lds(16B), XOR-chunk-swizzled,
// shared by both i-tiles. Softmax stats are per-lane scalars (q = ln).
// ---------------------------------------------------------------------------
__global__ __launch_bounds__(256) void attn_mfma(const short* __restrict__ qb,
                                                 const short* __restrict__ kb,
                                                 const short* __restrict__ vt,
                                                 short* __restrict__ o) {
    __shared__ __align__(16) short sK[64 * 128];    // 16 KB (row=j, 16 chunks)
    __shared__ __align__(16) short sV[128 * 64];    // 16 KB (row=d, 8 chunks)

    const int bid = blockIdx.x;
    const int p = bid & 15;
    const int bh = bid >> 4;
    const int h = bh & (HEADS - 1);
    const int b = bh >> 4;
    const int itH = 31 - p, itL = p;
    const int i0H = itH * 64, i0L = itL * 64;

    const int tid = threadIdx.x;
    const int w = tid >> 6;
    const int lane = tid & 63;
    const int ln = lane & 15;
    const int qr = lane >> 4;

    // Q B-fragments for this wave's 16 rows of each tile (regs for whole loop)
    const size_t qrowH = ((size_t)(b * SEQ + i0H + w * 16 + ln)) * INNER + h * DHEAD;
    const size_t qrowL = ((size_t)(b * SEQ + i0L + w * 16 + ln)) * INNER + h * DHEAD;
    short8 qfH[4], qfL[4];
#pragma unroll
    for (int ks = 0; ks < 4; ++ks) {
        qfH[ks] = *(const short8*)&qb[qrowH + ks * 32 + qr * 8];
        qfL[ks] = *(const short8*)&qb[qrowL + ks * 32 + qr * 8];
    }

    const f32x4 zero4 = {0.f, 0.f, 0.f, 0.f};
    f32x4 oH[8], oL[8];
#pragma unroll
    for (int dt = 0; dt < 8; ++dt) { oH[dt] = zero4; oL[dt] = zero4; }
    float mH = -3.0e38f, lHs = 0.f, mL = -3.0e38f, lLs = 0.f;

    // staging source pointers (per-lane, jt-invariant parts)
    const short* kbase = kb + (size_t)b * SEQ * DHEAD;
    const short* vbase = vt + (size_t)b * DHEAD * SEQ;
    const short* pK[4];
    const short* pV[4];
#pragma unroll
    for (int t = 0; t < 4; ++t) {
        int rk = w * 16 + t * 4 + (lane >> 4);            // K tile row 0..63
        int ck = (lane & 15) ^ swz_row(rk);               // logical chunk
        pK[t] = kbase + (size_t)rk * DHEAD + ck * 8;
        int rv = w * 32 + t * 8 + (lane >> 3);            // V tile row 0..127
        int cv = (lane & 7) ^ swz_row(rv);
        pV[t] = vbase + (size_t)rv * SEQ + cv * 8;
    }

    for (int jt = 0; jt <= itH; ++jt) {
        const bool doL = (jt <= itL);
        __syncthreads();   // all waves done reading previous tile
#pragma unroll
        for (int t = 0; t < 4; ++t)
            glds16(pK[t] + (size_t)jt * 64 * DHEAD, &sK[(w * 16 + t * 4) * 128]);
#pragma unroll
        for (int t = 0; t < 4; ++t)
            glds16(pV[t] + (size_t)jt * 64, &sV[(w * 32 + t * 8) * 64]);
        __syncthreads();   // drains vmcnt (glds) + barrier

        // S^T = K·Q^T. A-row j-interleave: m-tile nt, lane ln reads j row
        //   (nt>>1)*32 + (ln>>2)*8 + (nt&1)*4 + (ln&3)
        // so C element (qr*4+r) has j = (nt>>1)*32 + qr*8 + (nt&1)*4 + r.
        f32x4 sH[4], sL[4];
#pragma unroll
        for (int nt = 0; nt < 4; ++nt) { sH[nt] = zero4; sL[nt] = zero4; }
#pragma unroll
        for (int nt = 0; nt < 4; ++nt) {
            const int row = ((nt >> 1) << 5) + ((ln >> 2) << 3) + ((nt & 1) << 2) + (ln & 3);
            const int sw = ln & 7;   // == swz_row(row) for this map
#pragma unroll
            for (int ks = 0; ks < 4; ++ks) {
                short8 kf = *(const short8*)&sK[row * 128 + ((4 * ks + qr) ^ sw) * 8];
                sH[nt] = __builtin_amdgcn_mfma_f32_16x16x32_bf16(kf, qfH[ks], sH[nt], 0, 0, 0);
                if (doL)
                    sL[nt] = __builtin_amdgcn_mfma_f32_16x16x32_bf16(kf, qfL[ks], sL[nt], 0, 0, 0);
            }
        }

        // causal mask on diagonal tiles: j = jt*64 + jloc, i = i0 + w*16 + ln
        if (jt == itH) {
            const int iloc = w * 16 + ln;
#pragma unroll
            for (int nt = 0; nt < 4; ++nt)
#pragma unroll
                for (int r = 0; r < 4; ++r) {
                    int jloc = ((nt >> 1) << 5) + qr * 8 + ((nt & 1) << 2) + r;
                    if (jloc > iloc) sH[nt][r] = -3.0e38f;
                }
        }
        if (doL && jt == itL) {
            const int iloc = w * 16 + ln;
#pragma unroll
            for (int nt = 0; nt < 4; ++nt)
#pragma unroll
                for (int r = 0; r < 4; ++r) {
                    int jloc = ((nt >> 1) << 5) + qr * 8 + ((nt & 1) << 2) + r;
                    if (jloc > iloc) sL[nt][r] = -3.0e38f;
                }
        }

        // ---- tile H: online softmax (per-lane scalars) + P pack ----
        short8 pbH[2], pbL[2];
        {
            float smax = -3.0e38f;
#pragma unroll
            for (int nt = 0; nt < 4; ++nt)
#pragma unroll
                for (int r = 0; r < 4; ++r) smax = fmaxf(smax, sH[nt][r]);
            smax = fmaxf(smax, __shfl_xor(smax, 16));
            smax = fmaxf(smax, __shfl_xor(smax, 32));
            float mnew = fmaxf(mH, smax);
            float alpha = __expf(mH - mnew);
            mH = mnew;
            float rs = 0.f;
            float pv[4][4];
#pragma unroll
            for (int nt = 0; nt < 4; ++nt)
#pragma unroll
                for (int r = 0; r < 4; ++r) {
                    float e = __expf(sH[nt][r] - mnew);
                    pv[nt][r] = e;
                    rs += e;
                }
            rs += __shfl_xor(rs, 16);
            rs += __shfl_xor(rs, 32);
            lHs = lHs * alpha + rs;
#pragma unroll
            for (int dt = 0; dt < 8; ++dt)
#pragma unroll
                for (int r = 0; r < 4; ++r) oH[dt][r] *= alpha;
#pragma unroll
            for (int kb2 = 0; kb2 < 2; ++kb2) {
                short8 pb;
#pragma unroll
                for (int r = 0; r < 4; ++r) {
                    pb[r] = f2bf(pv[2 * kb2][r]);
                    pb[4 + r] = f2bf(pv[2 * kb2 + 1][r]);
                }
                pbH[kb2] = pb;
            }
        }
        // ---- tile L ----
        if (doL) {
            float smax = -3.0e38f;
#pragma unroll
            for (int nt = 0; nt < 4; ++nt)
#pragma unroll
                for (int r = 0; r < 4; ++r) smax = fmaxf(smax, sL[nt][r]);
            smax = fmaxf(smax, __shfl_xor(smax, 16));
            smax = fmaxf(smax, __shfl_xor(smax, 32));
            float mnew = fmaxf(mL, smax);
            float alpha = __expf(mL - mnew);
            mL = mnew;
            float rs = 0.f;
            float pv[4][4];
#pragma unroll
            for (int nt = 0; nt < 4; ++nt)
#pragma unroll
                for (int r = 0; r < 4; ++r) {
                    float e = __expf(sL[nt][r] - mnew);
                    pv[nt][r] = e;
                    rs += e;
                }
            rs += __shfl_xor(rs, 16);
            rs += __shfl_xor(rs, 32);
            lLs = lLs * alpha + rs;
#pragma unroll
            for (int dt = 0; dt < 8; ++dt)
#pragma unroll
                for (int r = 0; r < 4; ++r) oL[dt][r] *= alpha;
#pragma unroll
            for (int kb2 = 0; kb2 < 2; ++kb2) {
                short8 pb;
#pragma unroll
                for (int r = 0; r < 4; ++r) {
                    pb[r] = f2bf(pv[2 * kb2][r]);
                    pb[4 + r] = f2bf(pv[2 * kb2 + 1][r]);
                }
                pbL[kb2] = pb;
            }
        }

        // O^T += V^T · P^T  (A = V^T from LDS, shared; B = P^T from regs)
#pragma unroll
        for (int kb2 = 0; kb2 < 2; ++kb2) {
#pragma unroll
            for (int dt = 0; dt < 8; ++dt) {
                const int row = dt * 16 + ln;
                short8 vf = *(const short8*)&sV[row * 64 + ((4 * kb2 + qr) ^ swz_row(row)) * 8];
                oH[dt] = __builtin_amdgcn_mfma_f32_16x16x32_bf16(vf, pbH[kb2], oH[dt], 0, 0, 0);
                if (doL)
                    oL[dt] = __builtin_amdgcn_mfma_f32_16x16x32_bf16(vf, pbL[kb2], oL[dt], 0, 0, 0);
            }
        }
    }

    // epilogue: O^T element (d = dt*16 + qr*4 + r, q = ln) -> o[b, i, h, d]
    {
        const float invl = 1.f / lHs;
        short* orow = o + ((size_t)(b * SEQ + i0H + w * 16 + ln)) * INNER + h * DHEAD;
#pragma unroll
        for (int dt = 0; dt < 8; ++dt) {
            short4v sv = {f2bf(oH[dt][0] * invl), f2bf(oH[dt][1] * invl),
                          f2bf(oH[dt][2] * invl), f2bf(oH[dt][3] * invl)};
            *(short4v*)&orow[dt * 16 + qr * 4] = sv;
        }
    }
    {
        const float invl = 1.f / lLs;
        short* orow = o + ((size_t)(b * SEQ + i0L + w * 16 + ln)) * INNER + h * DHEAD;
#pragma unroll
        for (int dt = 0; dt < 8; ++dt) {
            short4v sv = {f2bf(oL[dt][0] * invl), f2bf(oL[dt][1] * invl),
                          f2bf(oL[dt][2] * invl), f2bf(oL[dt][3] * invl)};
            *(short4v*)&orow[dt * 16 + qr * 4] = sv;
        }
    }
}

// ---------------------------------------------------------------------------
extern "C" void kernel_launch(void* const* d_in, const int* in_sizes, int n_in,
                              void* d_out, int out_size, void* d_ws, size_t ws_size,
                              hipStream_t stream) {
    const float* x    = (const float*)d_in[0];   // [2, 2048, 2048]
    const float* Wq   = (const float*)d_in[1];   // [2048, 2048]
    const float* Wkv  = (const float*)d_in[2];   // [2048, 256]
    const float* Wout = (const float*)d_in[3];   // [2048, 2048]
    float* out = (float*)d_out;                  // [2, 2048, 2048]

    // workspace (bf16 shorts) — 47 MB total
    short* xb    = (short*)d_ws;                        // MROWS*DIM      16.8 MB
    short* Wt    = xb + (size_t)MROWS * DIM;            // 2048*2048       8.4 MB (Wq then Wout)
    short* Wkvt  = Wt + (size_t)DIM * INNER;            // 256*2048        1 MB
    short* qb    = Wkvt + (size_t)256 * DIM;            // MROWS*INNER    16.8 MB
    short* kvbb  = qb + (size_t)MROWS * INNER;          // MROWS*256       2 MB
    short* kb    = kvbb + (size_t)MROWS * 256;          // MROWS*128       1 MB
    short* vt    = kb + (size_t)MROWS * DHEAD;          // BATCH*128*SEQ   1 MB
    short* ob    = xb;                                  // alias: xb dead after gemm2

    cast_x<<<(MROWS * DIM / 4) / 256, 256, 0, stream>>>(x, xb);
    tcast<<<dim3(INNER / 64, DIM / 64), 256, 0, stream>>>(Wq, Wt, DIM, INNER);
    tcast<<<dim3(256 / 64, DIM / 64), 256, 0, stream>>>(Wkv, Wkvt, DIM, 256);
    gemm_bt<<<dim3(INNER / 128, MROWS / 128), 256, 0, stream>>>(xb, Wt, qb, MROWS, INNER, DIM, 1);
    gemm_bt<<<dim3(256 / 128, MROWS / 128), 256, 0, stream>>>(xb, Wkvt, kvbb, MROWS, 256, DIM, 1);
    rope_q_ip<<<(MROWS * HEADS * 64) / 256, 256, 0, stream>>>(qb);
    rope_k_bf<<<(MROWS * 64) / 256, 256, 0, stream>>>(kvbb, kb);
    vtrans_bf<<<BATCH * 64, 256, 0, stream>>>(kvbb, vt);
    attn_mfma<<<BATCH * HEADS * 16, 256, 0, stream>>>(qb, kb, vt, ob);
    tcast<<<dim3(DIM / 64, INNER / 64), 256, 0, stream>>>(Wout, Wt, INNER, DIM);
    gemm_bt<<<dim3(DIM / 128, MROWS / 128), 256, 0, stream>>>(ob, Wt, out, MROWS, DIM, INNER, 0);
}

// Round 5
// 353.518 us; speedup vs baseline: 1.6417x; 1.6417x over previous
//
#include <hip/hip_runtime.h>
#include <hip/hip_bf16.h>
#include <cstddef>
#include <cstdint>

// Problem constants (fixed by the reference)
#define BATCH 2
#define SEQ   2048
#define DIM   2048
#define HEADS 16
#define DHEAD 128
#define INNER (HEADS * DHEAD)   // 2048
#define MROWS (BATCH * SEQ)     // 4096
#define ATT_SCALE 0.08838834764831845f  // 128^-0.5
// q scale with log2(e) folded in, so softmax can use native exp2
#define QK_SCALE (0.08838834764831845f * 1.4426950408889634f)
#define NEG_LOG2_10000_DIV64 (-13.287712379549449f / 64.0f)

typedef __attribute__((ext_vector_type(8))) short short8;  // 8 bf16 = 4 VGPRs
typedef __attribute__((ext_vector_type(4))) short short4v;
typedef __attribute__((ext_vector_type(4))) float f32x4;   // MFMA C/D

// fp32 -> bf16 round-to-nearest-even (bit-level)
static __device__ __forceinline__ short f2bf(float x) {
    uint32_t u = __float_as_uint(x);
    uint32_t r = (u + 0x7fffu + ((u >> 16) & 1u)) >> 16;
    return (short)r;
}
static __device__ __forceinline__ float bf2f(short s) {
    return __uint_as_float(((uint32_t)(uint16_t)s) << 16);
}

// async global->LDS, 16 B per lane; LDS dst = uniform base + lane*16
static __device__ __forceinline__ void glds16(const short* g, short* l) {
    __builtin_amdgcn_global_load_lds(
        (const __attribute__((address_space(1))) unsigned int*)g,
        (__attribute__((address_space(3))) unsigned int*)l, 16, 0, 0);
}

// chunk swizzle for unpadded LDS tiles (chunk = 16 B): phys = logical ^ SWZ(row)
static __device__ __forceinline__ int swz_row(int r) {
    return (r & 3) | ((r >> 1) & 4);   // bits {0,1,3} of row -> 8 values
}

// ---------------------------------------------------------------------------
// x fp32 -> bf16
// ---------------------------------------------------------------------------
__global__ __launch_bounds__(256) void cast_x(const float* __restrict__ x,
                                              short* __restrict__ xb) {
    int i = blockIdx.x * 256 + threadIdx.x;
    float4 v = ((const float4*)x)[i];
    short4v s = {f2bf(v.x), f2bf(v.y), f2bf(v.z), f2bf(v.w)};
    ((short4v*)xb)[i] = s;
}

// ---------------------------------------------------------------------------
// W fp32 [R][C] -> Wt bf16 [C][R]
// ---------------------------------------------------------------------------
__global__ __launch_bounds__(256) void tcast(const float* __restrict__ W,
                                             short* __restrict__ Wt,
                                             int R, int C) {
    __shared__ float tile[64][65];
    const int c0 = blockIdx.x * 64, r0 = blockIdx.y * 64;
    const int tid = threadIdx.x;
#pragma unroll
    for (int t = 0; t < 16; ++t) {
        int idx = tid + t * 256;
        int row = idx >> 6, col = idx & 63;
        tile[row][col] = W[(size_t)(r0 + row) * C + c0 + col];
    }
    __syncthreads();
#pragma unroll
    for (int t = 0; t < 16; ++t) {
        int idx = tid + t * 256;
        int r = idx >> 6, c = idx & 63;
        Wt[(size_t)(c0 + r) * R + r0 + c] = f2bf(tile[c][r]);
    }
}

// ---------------------------------------------------------------------------
// bf16 MFMA GEMM (m97 structure): C[M,N] = A[M,K] @ Bt[N,K]^T  (unchanged)
// ---------------------------------------------------------------------------
__global__ __launch_bounds__(256) void gemm_bt(const short* __restrict__ A,
                                               const short* __restrict__ Bt,
                                               void* __restrict__ Cp,
                                               int M, int N, int K, int c_bf16) {
    __shared__ __align__(16) short sA[128 * 32];
    __shared__ __align__(16) short sB[128 * 32];

    const int tid = threadIdx.x;
    const int w = tid >> 6, lane = tid & 63;
    const int ln = lane & 15, qr = lane >> 4;
    const int bm = blockIdx.y * 128, bn = blockIdx.x * 128;
    const int wm = (w >> 1) * 64, wn = (w & 1) * 64;

    const f32x4 zero4 = {0.f, 0.f, 0.f, 0.f};
    f32x4 acc[4][4];
#pragma unroll
    for (int mt = 0; mt < 4; ++mt)
#pragma unroll
        for (int nt = 0; nt < 4; ++nt) acc[mt][nt] = zero4;

    const int srow = lane >> 2;
    const int schunk = (lane & 3) * 8;
    const short* pA = A + (size_t)(bm + w * 32 + srow) * K + schunk;
    const short* pB = Bt + (size_t)(bn + w * 32 + srow) * K + schunk;
    short* lA = &sA[(w * 32) * 32];
    short* lB = &sB[(w * 32) * 32];

    for (int k0 = 0; k0 < K; k0 += 32) {
        __syncthreads();
        glds16(pA + k0, lA);
        glds16(pA + k0 + (size_t)16 * K, lA + 512);
        glds16(pB + k0, lB);
        glds16(pB + k0 + (size_t)16 * K, lB + 512);
        __syncthreads();

        short8 af[4], bfr[4];
#pragma unroll
        for (int mt = 0; mt < 4; ++mt)
            af[mt] = *(const short8*)&sA[(wm + mt * 16 + ln) * 32 + qr * 8];
#pragma unroll
        for (int nt = 0; nt < 4; ++nt)
            bfr[nt] = *(const short8*)&sB[(wn + nt * 16 + ln) * 32 + qr * 8];
#pragma unroll
        for (int mt = 0; mt < 4; ++mt)
#pragma unroll
            for (int nt = 0; nt < 4; ++nt)
                acc[mt][nt] = __builtin_amdgcn_mfma_f32_16x16x32_bf16(
                    af[mt], bfr[nt], acc[mt][nt], 0, 0, 0);
    }

    if (c_bf16) {
        short* C = (short*)Cp;
#pragma unroll
        for (int mt = 0; mt < 4; ++mt)
#pragma unroll
            for (int nt = 0; nt < 4; ++nt)
#pragma unroll
                for (int r = 0; r < 4; ++r)
                    C[(size_t)(bm + wm + mt * 16 + qr * 4 + r) * N +
                      bn + wn + nt * 16 + ln] = f2bf(acc[mt][nt][r]);
    } else {
        float* C = (float*)Cp;
#pragma unroll
        for (int mt = 0; mt < 4; ++mt)
#pragma unroll
            for (int nt = 0; nt < 4; ++nt)
#pragma unroll
                for (int r = 0; r < 4; ++r)
                    C[(size_t)(bm + wm + mt * 16 + qr * 4 + r) * N +
                      bn + wn + nt * 16 + ln] = acc[mt][nt][r];
    }
}

// ---------------------------------------------------------------------------
// RoPE kernels. rope_q_ip folds QK_SCALE (ATT_SCALE * log2 e) into q so the
// attention softmax can use native exp2.
// ---------------------------------------------------------------------------
__global__ __launch_bounds__(256) void rope_q_ip(short* __restrict__ qb) {
    int idx = blockIdx.x * 256 + threadIdx.x;
    int j = idx & 63;
    int rh = idx >> 6;
    int pos = (rh >> 4) & (SEQ - 1);
    short* row = qb + ((size_t)rh << 7);
    float a = bf2f(row[j]);
    float b = bf2f(row[j + 64]);
    float ang = (float)pos * exp2f((float)j * NEG_LOG2_10000_DIV64);
    float c = cosf(ang), s = sinf(ang);
    row[j]      = f2bf((a * c - b * s) * QK_SCALE);
    row[j + 64] = f2bf((b * c + a * s) * QK_SCALE);
}

__global__ __launch_bounds__(256) void rope_k_bf(const short* __restrict__ kvbb,
                                                 short* __restrict__ kb) {
    int idx = blockIdx.x * 256 + threadIdx.x;
    int j = idx & 63;
    int bn = idx >> 6;
    int pos = bn & (SEQ - 1);
    const short* row = kvbb + (size_t)bn * 256;
    short* orow = kb + ((size_t)bn << 7);
    float a = bf2f(row[j]);
    float b = bf2f(row[j + 64]);
    float ang = (float)pos * exp2f((float)j * NEG_LOG2_10000_DIV64);
    float c = cosf(ang), s = sinf(ang);
    orow[j]      = f2bf(a * c - b * s);
    orow[j + 64] = f2bf(b * c + a * s);
}

__global__ __launch_bounds__(256) void vtrans_bf(const short* __restrict__ kvbb,
                                                 short* __restrict__ vt) {
    __shared__ float tile[64][65];
    const int bb = blockIdx.x;
    const int b = bb >> 6;
    const int tile_id = bb & 63;
    const int p0 = (tile_id >> 1) * 64;
    const int d0 = (tile_id & 1) * 64;
    const int tid = threadIdx.x;
#pragma unroll
    for (int t = 0; t < 16; ++t) {
        int idx = tid + t * 256;
        int row = idx >> 6, col = idx & 63;
        tile[row][col] = bf2f(kvbb[((size_t)(b * SEQ) + p0 + row) * 256 + 128 + d0 + col]);
    }
    __syncthreads();
#pragma unroll
    for (int t = 0; t < 16; ++t) {
        int idx = tid + t * 256;
        int r = idx >> 6, c = idx & 63;
        vt[((size_t)(b * DHEAD) + d0 + r) * SEQ + p0 + c] = f2bf(tile[c][r]);
    }
}

// ---------------------------------------------------------------------------
// MFMA flash attention v3 (causal, MQA).
// Block = 256 thr = 4 waves, processes i-tiles {31-p, p} SEQUENTIALLY ->
// exactly 33 j-iterations per block, 512 perfectly balanced blocks, and
// per-phase register state stays small (no r4 register blowup).
// Transposed compute (verified in r4): S^T = K·Q^T with a j-interleaved
// A-row map so the S^T C-layout is directly the PV B-fragment layout —
// P never leaves registers. O^T = V^T·P^T. Softmax stats per-lane scalars.
// K/V staged via global_load_lds(16B) with XOR-chunk swizzle (no conflicts).
// Softmax in base-2 (log2 e folded into q scale).
// ---------------------------------------------------------------------------
__global__ __launch_bounds__(256) void attn_mfma(const short* __restrict__ qb,
                                                 const short* __restrict__ kb,
                                                 const short* __restrict__ vt,
                                                 short* __restrict__ o) {
    __shared__ __align__(16) short sK[64 * 128];    // 16 KB (row=j, 16 chunks)
    __shared__ __align__(16) short sV[128 * 64];    // 16 KB (row=d, 8 chunks)

    const int bid = blockIdx.x;
    const int p = bid & 15;
    const int bh = bid >> 4;
    const int h = bh & (HEADS - 1);
    const int b = bh >> 4;

    const int tid = threadIdx.x;
    const int w = tid >> 6;
    const int lane = tid & 63;
    const int ln = lane & 15;
    const int qr = lane >> 4;

    const short* kbase = kb + (size_t)b * SEQ * DHEAD;
    const short* vbase = vt + (size_t)b * DHEAD * SEQ;

    // per-lane staging offsets (phase/jt-invariant)
    int offK[4], offV[4];
#pragma unroll
    for (int t = 0; t < 4; ++t) {
        int rk = w * 16 + t * 4 + (lane >> 4);            // K tile row 0..63
        int ck = (lane & 15) ^ swz_row(rk);               // logical chunk
        offK[t] = rk * DHEAD + ck * 8;
        int rv = w * 32 + t * 8 + (lane >> 3);            // V tile row 0..127
        int cv = (lane & 7) ^ swz_row(rv);
        offV[t] = rv * SEQ + cv * 8;
    }

    for (int ph = 0; ph < 2; ++ph) {
        const int it = ph ? p : (31 - p);
        const int i0 = it * 64;

        // Q B-fragments for this wave's 16 rows (regs for whole phase)
        const size_t qrow = ((size_t)(b * SEQ + i0 + w * 16 + ln)) * INNER + h * DHEAD;
        short8 qf[4];
#pragma unroll
        for (int ks = 0; ks < 4; ++ks)
            qf[ks] = *(const short8*)&qb[qrow + ks * 32 + qr * 8];

        const f32x4 zero4 = {0.f, 0.f, 0.f, 0.f};
        f32x4 oa[8];
#pragma unroll
        for (int dt = 0; dt < 8; ++dt) oa[dt] = zero4;
        float m = -3.0e38f, l = 0.f;

        for (int jt = 0; jt <= it; ++jt) {
            __syncthreads();   // all waves done reading previous tile
#pragma unroll
            for (int t = 0; t < 4; ++t)
                glds16(kbase + (size_t)jt * 64 * DHEAD + offK[t],
                       &sK[(w * 16 + t * 4) * 128]);
#pragma unroll
            for (int t = 0; t < 4; ++t)
                glds16(vbase + (size_t)jt * 64 + offV[t],
                       &sV[(w * 32 + t * 8) * 64]);
            __syncthreads();   // drains vmcnt (glds) + barrier

            // S^T = K·Q^T. A-row j-interleave: C elem (nt, reg r) has
            // j = (nt>>1)*32 + qr*8 + (nt&1)*4 + r, q-col = ln.
            f32x4 sacc[4];
#pragma unroll
            for (int nt = 0; nt < 4; ++nt) sacc[nt] = zero4;
#pragma unroll
            for (int nt = 0; nt < 4; ++nt) {
                const int row = ((nt >> 1) << 5) + ((ln >> 2) << 3) +
                                ((nt & 1) << 2) + (ln & 3);
                const int sw = ln & 7;   // == swz_row(row) for this map
#pragma unroll
                for (int ks = 0; ks < 4; ++ks) {
                    short8 kf = *(const short8*)&sK[row * 128 + ((4 * ks + qr) ^ sw) * 8];
                    sacc[nt] = __builtin_amdgcn_mfma_f32_16x16x32_bf16(
                        kf, qf[ks], sacc[nt], 0, 0, 0);
                }
            }

            // causal mask on diagonal tile
            if (jt == it) {
                const int iloc = w * 16 + ln;
#pragma unroll
                for (int nt = 0; nt < 4; ++nt)
#pragma unroll
                    for (int r = 0; r < 4; ++r) {
                        int jloc = ((nt >> 1) << 5) + qr * 8 + ((nt & 1) << 2) + r;
                        if (jloc > iloc) sacc[nt][r] = -3.0e38f;
                    }
            }

            // online softmax (base-2; per-lane scalars, 2 shuffles per stat)
            float smax = -3.0e38f;
#pragma unroll
            for (int nt = 0; nt < 4; ++nt)
#pragma unroll
                for (int r = 0; r < 4; ++r) smax = fmaxf(smax, sacc[nt][r]);
            smax = fmaxf(smax, __shfl_xor(smax, 16));
            smax = fmaxf(smax, __shfl_xor(smax, 32));
            const float mold = m;
            m = fmaxf(m, smax);
            const float alpha = exp2f(mold - m);

            float rs = 0.f;
            float pv[4][4];
#pragma unroll
            for (int nt = 0; nt < 4; ++nt)
#pragma unroll
                for (int r = 0; r < 4; ++r) {
                    float e = exp2f(sacc[nt][r] - m);
                    pv[nt][r] = e;
                    rs += e;
                }
            rs += __shfl_xor(rs, 16);
            rs += __shfl_xor(rs, 32);
            l = l * alpha + rs;

            // rescale O only if some lane's max moved (wave-uniform branch)
            if (__any(mold != m)) {
#pragma unroll
                for (int dt = 0; dt < 8; ++dt)
#pragma unroll
                    for (int r = 0; r < 4; ++r) oa[dt][r] *= alpha;
            }

            // pack P^T B-fragments (chunk kb2: j = kb2*32 + qr*8 + e)
            short8 pb[2];
#pragma unroll
            for (int kb2 = 0; kb2 < 2; ++kb2) {
#pragma unroll
                for (int r = 0; r < 4; ++r) {
                    pb[kb2][r] = f2bf(pv[2 * kb2][r]);
                    pb[kb2][4 + r] = f2bf(pv[2 * kb2 + 1][r]);
                }
            }

            // O^T += V^T · P^T  (A = V^T from LDS, B = P^T from regs)
#pragma unroll
            for (int kb2 = 0; kb2 < 2; ++kb2) {
#pragma unroll
                for (int dt = 0; dt < 8; ++dt) {
                    const int row = dt * 16 + ln;
                    short8 vf = *(const short8*)&sV[row * 64 +
                        ((4 * kb2 + qr) ^ swz_row(row)) * 8];
                    oa[dt] = __builtin_amdgcn_mfma_f32_16x16x32_bf16(
                        vf, pb[kb2], oa[dt], 0, 0, 0);
                }
            }
        }

        // epilogue: O^T elem (d = dt*16 + qr*4 + r, q = ln) -> o[b, i, h, d]
        const float invl = 1.f / l;
        short* orow = o + ((size_t)(b * SEQ + i0 + w * 16 + ln)) * INNER + h * DHEAD;
#pragma unroll
        for (int dt = 0; dt < 8; ++dt) {
            short4v sv = {f2bf(oa[dt][0] * invl), f2bf(oa[dt][1] * invl),
                          f2bf(oa[dt][2] * invl), f2bf(oa[dt][3] * invl)};
            *(short4v*)&orow[dt * 16 + qr * 4] = sv;
        }
    }
}

// ---------------------------------------------------------------------------
extern "C" void kernel_launch(void* const* d_in, const int* in_sizes, int n_in,
                              void* d_out, int out_size, void* d_ws, size_t ws_size,
                              hipStream_t stream) {
    const float* x    = (const float*)d_in[0];   // [2, 2048, 2048]
    const float* Wq   = (const float*)d_in[1];   // [2048, 2048]
    const float* Wkv  = (const float*)d_in[2];   // [2048, 256]
    const float* Wout = (const float*)d_in[3];   // [2048, 2048]
    float* out = (float*)d_out;                  // [2, 2048, 2048]

    // workspace (bf16 shorts) — 47 MB total
    short* xb    = (short*)d_ws;                        // MROWS*DIM      16.8 MB
    short* Wt    = xb + (size_t)MROWS * DIM;            // 2048*2048       8.4 MB (Wq then Wout)
    short* Wkvt  = Wt + (size_t)DIM * INNER;            // 256*2048        1 MB
    short* qb    = Wkvt + (size_t)256 * DIM;            // MROWS*INNER    16.8 MB
    short* kvbb  = qb + (size_t)MROWS * INNER;          // MROWS*256       2 MB
    short* kb    = kvbb + (size_t)MROWS * 256;          // MROWS*128       1 MB
    short* vt    = kb + (size_t)MROWS * DHEAD;          // BATCH*128*SEQ   1 MB
    short* ob    = xb;                                  // alias: xb dead after gemm2

    cast_x<<<(MROWS * DIM / 4) / 256, 256, 0, stream>>>(x, xb);
    tcast<<<dim3(INNER / 64, DIM / 64), 256, 0, stream>>>(Wq, Wt, DIM, INNER);
    tcast<<<dim3(256 / 64, DIM / 64), 256, 0, stream>>>(Wkv, Wkvt, DIM, 256);
    gemm_bt<<<dim3(INNER / 128, MROWS / 128), 256, 0, stream>>>(xb, Wt, qb, MROWS, INNER, DIM, 1);
    gemm_bt<<<dim3(256 / 128, MROWS / 128), 256, 0, stream>>>(xb, Wkvt, kvbb, MROWS, 256, DIM, 1);
    rope_q_ip<<<(MROWS * HEADS * 64) / 256, 256, 0, stream>>>(qb);
    rope_k_bf<<<(MROWS * 64) / 256, 256, 0, stream>>>(kvbb, kb);
    vtrans_bf<<<BATCH * 64, 256, 0, stream>>>(kvbb, vt);
    attn_mfma<<<BATCH * HEADS * 16, 256, 0, stream>>>(qb, kb, vt, ob);
    tcast<<<dim3(DIM / 64, INNER / 64), 256, 0, stream>>>(Wout, Wt, INNER, DIM);
    gemm_bt<<<dim3(DIM / 128, MROWS / 128), 256, 0, stream>>>(ob, Wt, out, MROWS, DIM, INNER, 0);
}